// Round 7
// baseline (786.913 us; speedup 1.0000x reference)
//
#include <hip/hip_runtime.h>
#include <stdint.h>
#include <math.h>

// (B,H,SQ,SK,D,DV) = (2,16,2048,2048,64,64)
// out = (softmax(q k^T) * 0.5) with dropout p=0.1 (jax threefry key 42, partitionable) @ v
// R7: dropout mask generated by a dedicated pure-int kernel (1 bit/elem, 16.8 MB ws);
// attention k-loop reads mask bits (3 VALU/elem) instead of running threefry (74/elem).
// Empirical VALU rate ~3.2 cyc/wave-instr (R1/R6 calibration) -> threefry floor ~200 us.
namespace {
constexpr int Bb = 2, Hh = 16, SQc = 2048, SKc = 2048, Dc = 64, DVc = 64;
constexpr int TK = 64;
constexpr uint32_t NMASK = (uint32_t)Bb * Hh * SQc * SKc;  // 2^27 elements

typedef __attribute__((ext_vector_type(8))) short short8;   // MFMA A/B frag (8 bf16)
typedef __attribute__((ext_vector_type(4))) float f32x4;    // MFMA C/D frag

__device__ __forceinline__ uint32_t rotl_(uint32_t x, int r) {
  return __builtin_amdgcn_alignbit(x, x, 32 - r);  // 1-instr rotate
}

// JAX threefry2x32, key=(0,42), partitionable: bits(i)=o0^o1 of threefry((0,42),(0,i)).
// keep iff bits < 0xE6666600 (exact integer form of uniform(bits) < 0.9f). VERIFIED R1-R6.
__device__ __forceinline__ uint32_t tf_bits(uint32_t ctr) {
  const uint32_t ks1 = 42u, ks2 = 0x1BD11BDAu ^ 42u;
  uint32_t x0 = 0u;
  uint32_t x1 = ctr + ks1;
#define TFR(r) { x0 += x1; x1 = rotl_(x1, r); x1 ^= x0; }
  TFR(13) TFR(15) TFR(26) TFR(6)
  x0 += ks1; x1 += ks2 + 1u;
  TFR(17) TFR(29) TFR(16) TFR(24)
  x0 += ks2; x1 += 0u + 2u;
  TFR(13) TFR(15) TFR(26) TFR(6)
  x0 += 0u; x1 += ks1 + 3u;
  TFR(17) TFR(29) TFR(16) TFR(24)
  x0 += ks1; x1 += ks2 + 4u;
  TFR(13) TFR(15) TFR(26) TFR(6)
  x0 += ks2; x1 += 0u + 5u;
#undef TFR
  return x0 ^ x1;
}

__device__ __forceinline__ uint32_t f2bf_u(float x) {  // RNE bf16 (finite x), low 16 bits
  uint32_t u = __float_as_uint(x);
  u += 0x7FFFu + ((u >> 16) & 1u);
  return u >> 16;
}
__device__ __forceinline__ uint32_t bfround(float x) {  // RNE bf16 in bits 31:16
  uint32_t u = __float_as_uint(x);
  return u + 0x7FFFu + ((u >> 16) & 1u);
}
}  // namespace

// ---- mask generator: word w covers flat elements [w*32, w*32+32), bit j = keep ----
// Pure int-ALU, 32 independent 74-op chains/thread -> ~95% VALU issue.
__global__ __launch_bounds__(256) void mask_kernel(uint32_t* __restrict__ M) {
  const uint32_t T = blockIdx.x * 256 + threadIdx.x;  // word index
  const uint32_t base = T * 32u;
  uint32_t word = 0u;
#pragma unroll 8
  for (int j = 31; j >= 0; --j)
    word = (word << 1) | (tf_bits(base + (uint32_t)j) < 0xE6666600u ? 1u : 0u);
  M[T] = word;
}

// Pre-pass: K -> Kh (bf16 hi) + Kl (bf16 residual), row-major [h][sk][d];
//           V -> Vt bf16 transposed [h][dv][sk].
__global__ __launch_bounds__(256) void prep_kernel(
    const float* __restrict__ k, const float* __restrict__ v,
    unsigned short* __restrict__ Khg, unsigned short* __restrict__ Klg,
    unsigned short* __restrict__ Vtg) {
  __shared__ float Vs[64 * 65];
  const int t = threadIdx.x;
  const int h = blockIdx.x >> 5;
  const int skt = blockIdx.x & 31;
  const size_t base = ((size_t)h * SKc + skt * 64) * Dc;
#pragma unroll
  for (int i = 0; i < 4; ++i) {
    int idx = t + 256 * i;
    int row = idx >> 4, d0 = (idx & 15) << 2;
    float4 kv = *(const float4*)(k + base + row * Dc + d0);
    uint32_t hx = f2bf_u(kv.x), hy = f2bf_u(kv.y), hz = f2bf_u(kv.z), hw = f2bf_u(kv.w);
    uint32_t lx = f2bf_u(kv.x - __uint_as_float(hx << 16));
    uint32_t ly = f2bf_u(kv.y - __uint_as_float(hy << 16));
    uint32_t lz = f2bf_u(kv.z - __uint_as_float(hz << 16));
    uint32_t lw = f2bf_u(kv.w - __uint_as_float(hw << 16));
    *(ushort4*)(Khg + base + row * Dc + d0) =
        make_ushort4((unsigned short)hx, (unsigned short)hy, (unsigned short)hz, (unsigned short)hw);
    *(ushort4*)(Klg + base + row * Dc + d0) =
        make_ushort4((unsigned short)lx, (unsigned short)ly, (unsigned short)lz, (unsigned short)lw);
    float4 vv = *(const float4*)(v + base + row * Dc + d0);  // DVc == Dc
    *(float4*)(&Vs[row * 65 + d0]) = vv;
  }
  __syncthreads();
  const int dv = t >> 2, sk0 = (t & 3) << 4;
  unsigned short tmp[16];
#pragma unroll
  for (int j = 0; j < 16; ++j) tmp[j] = (unsigned short)f2bf_u(Vs[(sk0 + j) * 65 + dv]);
  unsigned short* vp = Vtg + ((size_t)h * DVc + dv) * SKc + skt * 64 + sk0;
  *(short8*)(vp) = *(const short8*)&tmp[0];
  *(short8*)(vp + 8) = *(const short8*)&tmp[8];
}

__global__ __launch_bounds__(256, 6) void attn_main(
    const float* __restrict__ q, const unsigned short* __restrict__ Khg,
    const unsigned short* __restrict__ Klg, const unsigned short* __restrict__ Vtg,
    const uint32_t* __restrict__ M, float* __restrict__ out) {
  const int t = threadIdx.x;
  const int lane = t & 63;
  const int w = t >> 6;
  const int lm = lane & 15;
  const int quad = lane >> 4;
  const int qsub = w >> 1;   // which 16-q-row group (block covers 32 q rows)
  const int khalf = w & 1;   // which half of the 2048 keys

  // XCD swizzle: 256 consecutive vids (4 heads) per XCD -> K/V L2-resident
  const int vid = (blockIdx.x & 7) * 256 + (blockIdx.x >> 3);
  const int qt = vid & 63;
  const int h = (vid >> 6) & 15;
  const int b = vid >> 10;
  const int qrow = qt * 32 + qsub * 16 + lm;

  // ---- Q B-frags (fp32 -> split bf16 in regs), constant over k-loop ----
  short8 qh[2], ql[2];
  {
    const float* qp = q + (((size_t)(b * Hh + h)) * SQc + qrow) * Dc;
#pragma unroll
    for (int c = 0; c < 2; ++c) {
#pragma unroll
      for (int j2 = 0; j2 < 2; ++j2) {
        float4 x = *(const float4*)(qp + c * 32 + quad * 8 + j2 * 4);
        float xs[4] = {x.x, x.y, x.z, x.w};
#pragma unroll
        for (int j = 0; j < 4; ++j) {
          uint32_t hb = f2bf_u(xs[j]);
          float lo = xs[j] - __uint_as_float(hb << 16);
          qh[c][j2 * 4 + j] = (short)hb;
          ql[c][j2 * 4 + j] = (short)f2bf_u(lo);
        }
      }
    }
  }

  const unsigned short* kh_base = Khg + (size_t)h * SKc * Dc;
  const unsigned short* kl_base = Klg + (size_t)h * SKc * Dc;
  const unsigned short* vt_base = Vtg + (size_t)h * DVc * SKc;
  // mask row base: word index = flatrow*64 + khalf*32; +2 words per k-tile
  const uint32_t flatrow = (uint32_t)((b * Hh + h) * SQc + qrow);
  const uint32_t* mrow = M + (size_t)flatrow * 64 + khalf * 32;

  f32x4 acc[4] = {{0.f, 0.f, 0.f, 0.f}, {0.f, 0.f, 0.f, 0.f},
                  {0.f, 0.f, 0.f, 0.f}, {0.f, 0.f, 0.f, 0.f}};
  float l_i = 0.f;  // per-lane partial denominator (fixed m=0), reduced at the end

  // bpermute byte-addresses for the cross-quad P exchange (constant per lane)
  const int a0 = ((quad & 1) * 32 + lm) << 2;
  const int a1 = a0 + 64;
  const uint32_t sel = (quad >= 2) ? 0x07060302u : 0x05040100u;

  const int kt0 = khalf * 16;
  for (int kt = kt0; kt < kt0 + 16; ++kt) {
    // lane-invariant-per-tile K base for this tile (rows kt*64 + .. + lm)
    const unsigned short* khp = kh_base + (size_t)(kt * TK + lm) * Dc + quad * 8;
    const unsigned short* klp = kl_base + (size_t)(kt * TK + lm) * Dc + quad * 8;
    // mask words for this tile's 64-col window of row qrow
    const uint2 mw = *(const uint2*)(mrow + (kt - kt0) * 2);

#pragma unroll
    for (int c = 0; c < 2; ++c) {
      // ---- S^T for nb = 2c, 2c+1 (rows (2c)*16, (2c+1)*16): 3-term split ----
      f32x4 s0 = {0.f, 0.f, 0.f, 0.f}, s1 = {0.f, 0.f, 0.f, 0.f};
#pragma unroll
      for (int d = 0; d < 2; ++d) {
        short8 kh0 = *(const short8*)(khp + (2 * c) * 16 * Dc + d * 32);
        short8 kl0 = *(const short8*)(klp + (2 * c) * 16 * Dc + d * 32);
        s0 = __builtin_amdgcn_mfma_f32_16x16x32_bf16(kh0, qh[d], s0, 0, 0, 0);
        s0 = __builtin_amdgcn_mfma_f32_16x16x32_bf16(kl0, qh[d], s0, 0, 0, 0);
        s0 = __builtin_amdgcn_mfma_f32_16x16x32_bf16(kh0, ql[d], s0, 0, 0, 0);
        short8 kh1 = *(const short8*)(khp + (2 * c + 1) * 16 * Dc + d * 32);
        short8 kl1 = *(const short8*)(klp + (2 * c + 1) * 16 * Dc + d * 32);
        s1 = __builtin_amdgcn_mfma_f32_16x16x32_bf16(kh1, qh[d], s1, 0, 0, 0);
        s1 = __builtin_amdgcn_mfma_f32_16x16x32_bf16(kl1, qh[d], s1, 0, 0, 0);
        s1 = __builtin_amdgcn_mfma_f32_16x16x32_bf16(kh1, ql[d], s1, 0, 0, 0);
      }

      // ---- p = e^s (fixed m, fp32-safe); dropout via mask bits; pack bf16 pairs ----
      // chunk word: bits (quad*4+r) for p0 (cols c*32+quad*4+r), (16+quad*4+r) for p1
      const uint32_t sw = ((c == 0) ? mw.x : mw.y) >> (quad * 4);
      uint32_t pkc[4];
#pragma unroll
      for (int r = 0; r < 4; ++r) {
        float p0 = __expf(s0[r]);
        float p1 = __expf(s1[r]);
        l_i += p0 + p1;  // denominator over UNdropped probs
        uint32_t m0 = (uint32_t)((int32_t)(sw << (31 - r)) >> 31);        // keep ? ~0 : 0
        uint32_t m1 = (uint32_t)((int32_t)(sw << (31 - 16 - r)) >> 31);
        uint32_t u0 = bfround(p0) & m0;
        uint32_t u1 = bfround(p1) & m1;
        pkc[r] = __builtin_amdgcn_perm(u1, u0, 0x07060302u);  // (bf(p1)<<16)|bf(p0)
      }

      // ---- P^T B-frag for this sk-chunk via cross-quad bpermute ----
      short8 pb;
      {
        uint32_t e0 = (uint32_t)__builtin_amdgcn_ds_bpermute(a0, (int)pkc[0]);
        uint32_t e1 = (uint32_t)__builtin_amdgcn_ds_bpermute(a0, (int)pkc[1]);
        uint32_t e2 = (uint32_t)__builtin_amdgcn_ds_bpermute(a0, (int)pkc[2]);
        uint32_t e3 = (uint32_t)__builtin_amdgcn_ds_bpermute(a0, (int)pkc[3]);
        uint32_t f0 = (uint32_t)__builtin_amdgcn_ds_bpermute(a1, (int)pkc[0]);
        uint32_t f1 = (uint32_t)__builtin_amdgcn_ds_bpermute(a1, (int)pkc[1]);
        uint32_t f2 = (uint32_t)__builtin_amdgcn_ds_bpermute(a1, (int)pkc[2]);
        uint32_t f3 = (uint32_t)__builtin_amdgcn_ds_bpermute(a1, (int)pkc[3]);
        uint32_t w0 = __builtin_amdgcn_perm(e1, e0, sel);
        uint32_t w1 = __builtin_amdgcn_perm(e3, e2, sel);
        uint32_t w2 = __builtin_amdgcn_perm(f1, f0, sel);
        uint32_t w3 = __builtin_amdgcn_perm(f3, f2, sel);
        uint32_t tmp[4] = {w0, w1, w2, w3};
        pb = *(const short8*)tmp;  // B[k=quad*8+j][n=lm] for sk-chunk c
      }

      // ---- O^T += V^T(chunk c) . P^T(chunk c) ----
#pragma unroll
      for (int nb = 0; nb < 4; ++nb) {
        const unsigned short* vr =
            vt_base + (size_t)(nb * 16 + lm) * SKc + kt * TK + c * 32 + quad * 8;
        short8 vb = *(const short8*)vr;
        acc[nb] = __builtin_amdgcn_mfma_f32_16x16x32_bf16(vb, pb, acc[nb], 0, 0, 0);
      }
    }
  }

  // ---- reduce l across quads (once) ----
  l_i += __shfl_xor(l_i, 16);
  l_i += __shfl_xor(l_i, 32);

  // ---- combine the two k-halves via LDS (fixed m -> partials are summable) ----
  __shared__ float Lacc[2][16][72];  // [qsub][q=lm][dv], stride 72 floats
  __shared__ float Ll[2][16];
  if (khalf == 1) {
#pragma unroll
    for (int nb = 0; nb < 4; ++nb)
      *(f32x4*)&Lacc[qsub][lm][nb * 16 + quad * 4] = acc[nb];
    if (quad == 0) Ll[qsub][lm] = l_i;
  }
  __syncthreads();
  if (khalf == 0) {
    float lt = l_i + Ll[qsub][lm];
    float sc = (0.5f / 0.9f) / lt;
    float* op = out + (((size_t)(b * Hh + h)) * SQc + qrow) * DVc;
#pragma unroll
    for (int nb = 0; nb < 4; ++nb) {
      f32x4 other = *(const f32x4*)&Lacc[qsub][lm][nb * 16 + quad * 4];
      float4 o = make_float4((acc[nb][0] + other[0]) * sc, (acc[nb][1] + other[1]) * sc,
                             (acc[nb][2] + other[2]) * sc, (acc[nb][3] + other[3]) * sc);
      *(float4*)(op + nb * 16 + quad * 4) = o;
    }
  }
}

extern "C" void kernel_launch(void* const* d_in, const int* in_sizes, int n_in,
                              void* d_out, int out_size, void* d_ws, size_t ws_size,
                              hipStream_t stream) {
  const float* q = (const float*)d_in[0];
  const float* k = (const float*)d_in[1];
  const float* v = (const float*)d_in[2];
  float* out = (float*)d_out;
  // ws layout: Kh (4 MB) | Kl (4 MB) | Vt (4 MB) | mask (16.78 MB)  ~= 29.4 MB
  unsigned short* Khg = (unsigned short*)d_ws;
  unsigned short* Klg = Khg + (size_t)Hh * SKc * Dc;
  unsigned short* Vtg = Klg + (size_t)Hh * SKc * Dc;
  uint32_t* Mg = (uint32_t*)(Vtg + (size_t)Hh * DVc * SKc);
  mask_kernel<<<dim3(NMASK / 32 / 256), 256, 0, stream>>>(Mg);
  prep_kernel<<<dim3(Hh * 32), 256, 0, stream>>>(k, v, Khg, Klg, Vtg);
  attn_main<<<dim3(Bb * Hh * (SQc / 32)), 256, 0, stream>>>(q, Khg, Klg, Vtg, Mg, out);
}

// Round 8
// 364.684 us; speedup vs baseline: 2.1578x; 2.1578x over previous
//
#include <hip/hip_runtime.h>
#include <stdint.h>
#include <math.h>

// (B,H,SQ,SK,D,DV) = (2,16,2048,2048,64,64)
// out = (softmax(q k^T) * 0.5) with dropout p=0.1 (jax threefry key 42, partitionable) @ v
// R8: LDS-staged block-shared K/V (global_load_lds w=16, XOR-swizzled tile layout,
// 4x traffic cut + full-line loads + LDS-latency chains); threefry inline (R7 proved
// it rides under the memory wall); fixed-m softmax; 64 q-rows/block, full-K loop.
namespace {
constexpr int Bb = 2, Hh = 16, SQc = 2048, SKc = 2048, Dc = 64, DVc = 64;
constexpr int TK = 64;

typedef __attribute__((ext_vector_type(8))) short short8;   // MFMA A/B frag (8 bf16)
typedef __attribute__((ext_vector_type(4))) float f32x4;    // MFMA C/D frag

__device__ __forceinline__ uint32_t rotl_(uint32_t x, int r) {
  return __builtin_amdgcn_alignbit(x, x, 32 - r);  // 1-instr rotate
}

// JAX threefry2x32, key=(0,42), partitionable: bits(i)=o0^o1 of threefry((0,42),(0,i)).
// keep iff bits < 0xE6666600 (exact integer form of uniform(bits) < 0.9f). VERIFIED R1-R7.
__device__ __forceinline__ uint32_t tf_bits(uint32_t ctr) {
  const uint32_t ks1 = 42u, ks2 = 0x1BD11BDAu ^ 42u;
  uint32_t x0 = 0u;
  uint32_t x1 = ctr + ks1;
#define TFR(r) { x0 += x1; x1 = rotl_(x1, r); x1 ^= x0; }
  TFR(13) TFR(15) TFR(26) TFR(6)
  x0 += ks1; x1 += ks2 + 1u;
  TFR(17) TFR(29) TFR(16) TFR(24)
  x0 += ks2; x1 += 0u + 2u;
  TFR(13) TFR(15) TFR(26) TFR(6)
  x0 += 0u; x1 += ks1 + 3u;
  TFR(17) TFR(29) TFR(16) TFR(24)
  x0 += ks1; x1 += ks2 + 4u;
  TFR(13) TFR(15) TFR(26) TFR(6)
  x0 += ks2; x1 += 0u + 5u;
#undef TFR
  return x0 ^ x1;
}

__device__ __forceinline__ uint32_t f2bf_u(float x) {  // RNE bf16 (finite x), low 16 bits
  uint32_t u = __float_as_uint(x);
  u += 0x7FFFu + ((u >> 16) & 1u);
  return u >> 16;
}
__device__ __forceinline__ uint32_t bfround(float x) {  // RNE bf16 in bits 31:16
  uint32_t u = __float_as_uint(x);
  return u + 0x7FFFu + ((u >> 16) & 1u);
}

// async global->LDS, 16 B per lane; LDS base wave-uniform, global addr per-lane
__device__ __forceinline__ void gl_lds16(const void* g, void* l) {
  __builtin_amdgcn_global_load_lds(
      (const __attribute__((address_space(1))) unsigned int*)g,
      (__attribute__((address_space(3))) unsigned int*)l, 16, 0, 0);
}
}  // namespace

// Pre-pass: tile-contiguous, XOR-swizzled layouts.
// Kh/Kl tile (h,kt): shorts[4096]; elem (row,col): row*64 + ((col>>3)^(row&7))*8 + (col&7)
// Vt tile  (h,kt): shorts[4096]; elem (dv,skl) = V[kt*64+skl][dv], same swizzle on skl.
__global__ __launch_bounds__(256) void prep_kernel(
    const float* __restrict__ k, const float* __restrict__ v,
    unsigned short* __restrict__ Khg, unsigned short* __restrict__ Klg,
    unsigned short* __restrict__ Vtg) {
  __shared__ float Vs[64 * 65];
  const int t = threadIdx.x;
  const int h = blockIdx.x >> 5;
  const int kt = blockIdx.x & 31;
  const size_t src = ((size_t)h * SKc + kt * 64) * Dc;
  const size_t tb = (size_t)(h * 32 + kt) * 4096;  // tile base (shorts)
#pragma unroll
  for (int i = 0; i < 4; ++i) {
    int idx = t + 256 * i;
    int row = idx >> 4, d0 = (idx & 15) << 2;
    float4 kv = *(const float4*)(k + src + row * Dc + d0);
    uint32_t hx = f2bf_u(kv.x), hy = f2bf_u(kv.y), hz = f2bf_u(kv.z), hw = f2bf_u(kv.w);
    uint32_t lx = f2bf_u(kv.x - __uint_as_float(hx << 16));
    uint32_t ly = f2bf_u(kv.y - __uint_as_float(hy << 16));
    uint32_t lz = f2bf_u(kv.z - __uint_as_float(hz << 16));
    uint32_t lw = f2bf_u(kv.w - __uint_as_float(hw << 16));
    int phys = row * 64 + (((d0 >> 3) ^ (row & 7)) << 3) + (d0 & 7);
    *(ushort4*)(Khg + tb + phys) =
        make_ushort4((unsigned short)hx, (unsigned short)hy, (unsigned short)hz, (unsigned short)hw);
    *(ushort4*)(Klg + tb + phys) =
        make_ushort4((unsigned short)lx, (unsigned short)ly, (unsigned short)lz, (unsigned short)lw);
    float4 vv = *(const float4*)(v + src + row * Dc + d0);  // DVc == Dc
    *(float4*)(&Vs[row * 65 + d0]) = vv;
  }
  __syncthreads();
  const int dv = t >> 2;
  const int j0 = (t & 3) << 1;  // two sk-chunks per thread
#pragma unroll
  for (int g = 0; g < 2; ++g) {
    int chunk = j0 + g;
    unsigned short tmp[8];
#pragma unroll
    for (int s = 0; s < 8; ++s)
      tmp[s] = (unsigned short)f2bf_u(Vs[(chunk * 8 + s) * 65 + dv]);
    *(short8*)(Vtg + tb + dv * 64 + ((chunk ^ (dv & 7)) << 3)) = *(const short8*)tmp;
  }
}

__global__ __launch_bounds__(256, 4) void attn_main(
    const float* __restrict__ q, const unsigned short* __restrict__ Khg,
    const unsigned short* __restrict__ Klg, const unsigned short* __restrict__ Vtg,
    float* __restrict__ out) {
  // staging buffer: Kh [0,4096) Kl [4096,8192) Vt [8192,12288) shorts = 24576 B
  __shared__ __align__(16) unsigned short stag[12288];

  const int t = threadIdx.x;
  const int lane = t & 63;
  const int w = t >> 6;        // wave = q-row group
  const int lm = lane & 15;
  const int quad = lane >> 4;

  // XCD swizzle: 128 consecutive vids (4 heads) per XCD -> K/V tiles L2-resident (3 MB)
  const int vid = (blockIdx.x & 7) * 128 + (blockIdx.x >> 3);
  const int qt = vid & 31;            // 32 q-tiles of 64 rows
  const int h = (vid >> 5) & 15;
  const int b = vid >> 9;
  const int qrow = qt * 64 + w * 16 + lm;

  // ---- Q B-frags (fp32 -> split bf16 in regs), constant over k-loop ----
  short8 qh[2], ql[2];
  {
    const float* qp = q + (((size_t)(b * Hh + h)) * SQc + qrow) * Dc;
#pragma unroll
    for (int c = 0; c < 2; ++c) {
#pragma unroll
      for (int j2 = 0; j2 < 2; ++j2) {
        float4 x = *(const float4*)(qp + c * 32 + quad * 8 + j2 * 4);
        float xs[4] = {x.x, x.y, x.z, x.w};
#pragma unroll
        for (int j = 0; j < 4; ++j) {
          uint32_t hb = f2bf_u(xs[j]);
          float lo = xs[j] - __uint_as_float(hb << 16);
          qh[c][j2 * 4 + j] = (short)hb;
          ql[c][j2 * 4 + j] = (short)f2bf_u(lo);
        }
      }
    }
  }

  const char* kh_t = (const char*)Khg + (size_t)(h * 32) * 8192;
  const char* kl_t = (const char*)Klg + (size_t)(h * 32) * 8192;
  const char* vt_t = (const char*)Vtg + (size_t)(h * 32) * 8192;

  f32x4 acc[4] = {{0.f, 0.f, 0.f, 0.f}, {0.f, 0.f, 0.f, 0.f},
                  {0.f, 0.f, 0.f, 0.f}, {0.f, 0.f, 0.f, 0.f}};
  float l_i = 0.f;  // fixed-m (m=0) partial denominator

  // swizzled LDS read offsets (shorts), loop-invariant:
  // chunk = d*4+quad (QK k-dim) or c*4+quad (PV sk-dim); phys = ((chunk)^(lm&7))*8
  const int e = lm & 7;
  const int a0s = lm * 64 + ((quad ^ e) << 3);        // chunks 0..3
  const int a1s = lm * 64 + (((quad + 4) ^ e) << 3);  // chunks 4..7

  // bpermute byte-addresses for the cross-quad P exchange (constant per lane)
  const int pa0 = ((quad & 1) * 32 + lm) << 2;
  const int pa1 = pa0 + 64;
  const uint32_t sel = (quad >= 2) ? 0x07060302u : 0x05040100u;

  uint32_t ctile = ((uint32_t)((b * Hh + h) * SQc + qrow)) * (uint32_t)SKc + (uint32_t)(quad * 4);

#pragma unroll 1
  for (int kt = 0; kt < 32; ++kt, ctile += TK) {
    __syncthreads();  // prior tile's ds_reads complete
    // ---- stage Kh/Kl/Vt tile (24 KB) via global_load_lds, 6 issues/thread ----
    {
      const size_t tile = (size_t)kt * 8192;
#pragma unroll
      for (int r = 0; r < 2; ++r) {
        int off = r * 4096 + w * 1024 + lane * 16;
        gl_lds16(kh_t + tile + off, (char*)stag + off);
        gl_lds16(kl_t + tile + off, (char*)stag + 8192 + off);
        gl_lds16(vt_t + tile + off, (char*)stag + 16384 + off);
      }
    }
    __syncthreads();  // staging complete (vmcnt(0) drained by barrier semantics)

#pragma unroll
    for (int c = 0; c < 2; ++c) {
      // ---- S^T for K-rows (2c)*16+lm, (2c+1)*16+lm : 3-term split bf16 ----
      f32x4 s0 = {0.f, 0.f, 0.f, 0.f}, s1 = {0.f, 0.f, 0.f, 0.f};
#pragma unroll
      for (int d = 0; d < 2; ++d) {
        const int ad = (d == 0) ? a0s : a1s;
        short8 kh0 = *(const short8*)&stag[ad + (2 * c) * 1024];
        short8 kl0 = *(const short8*)&stag[ad + (2 * c) * 1024 + 4096];
        s0 = __builtin_amdgcn_mfma_f32_16x16x32_bf16(kh0, qh[d], s0, 0, 0, 0);
        s0 = __builtin_amdgcn_mfma_f32_16x16x32_bf16(kl0, qh[d], s0, 0, 0, 0);
        s0 = __builtin_amdgcn_mfma_f32_16x16x32_bf16(kh0, ql[d], s0, 0, 0, 0);
        short8 kh1 = *(const short8*)&stag[ad + (2 * c + 1) * 1024];
        short8 kl1 = *(const short8*)&stag[ad + (2 * c + 1) * 1024 + 4096];
        s1 = __builtin_amdgcn_mfma_f32_16x16x32_bf16(kh1, qh[d], s1, 0, 0, 0);
        s1 = __builtin_amdgcn_mfma_f32_16x16x32_bf16(kl1, qh[d], s1, 0, 0, 0);
        s1 = __builtin_amdgcn_mfma_f32_16x16x32_bf16(kh1, ql[d], s1, 0, 0, 0);
      }

      // ---- p = e^s (fixed m, fp32-safe); inline threefry dropout; pack pairs ----
      uint32_t pkc[4];
#pragma unroll
      for (int r = 0; r < 4; ++r) {
        float p0 = __expf(s0[r]);
        float p1 = __expf(s1[r]);
        l_i += p0 + p1;  // denominator over UNdropped probs
        uint32_t b0 = tf_bits(ctile + (uint32_t)(c * 32 + r));
        uint32_t b1 = tf_bits(ctile + (uint32_t)(c * 32 + 16 + r));
        uint32_t u0 = (b0 < 0xE6666600u) ? bfround(p0) : 0u;
        uint32_t u1 = (b1 < 0xE6666600u) ? bfround(p1) : 0u;
        pkc[r] = __builtin_amdgcn_perm(u1, u0, 0x07060302u);  // (bf(p1)<<16)|bf(p0)
      }

      // ---- P^T B-frag via cross-quad bpermute (no barrier) ----
      short8 pb;
      {
        uint32_t e0 = (uint32_t)__builtin_amdgcn_ds_bpermute(pa0, (int)pkc[0]);
        uint32_t e1 = (uint32_t)__builtin_amdgcn_ds_bpermute(pa0, (int)pkc[1]);
        uint32_t e2 = (uint32_t)__builtin_amdgcn_ds_bpermute(pa0, (int)pkc[2]);
        uint32_t e3 = (uint32_t)__builtin_amdgcn_ds_bpermute(pa0, (int)pkc[3]);
        uint32_t f0 = (uint32_t)__builtin_amdgcn_ds_bpermute(pa1, (int)pkc[0]);
        uint32_t f1 = (uint32_t)__builtin_amdgcn_ds_bpermute(pa1, (int)pkc[1]);
        uint32_t f2 = (uint32_t)__builtin_amdgcn_ds_bpermute(pa1, (int)pkc[2]);
        uint32_t f3 = (uint32_t)__builtin_amdgcn_ds_bpermute(pa1, (int)pkc[3]);
        uint32_t w0 = __builtin_amdgcn_perm(e1, e0, sel);
        uint32_t w1 = __builtin_amdgcn_perm(e3, e2, sel);
        uint32_t w2 = __builtin_amdgcn_perm(f1, f0, sel);
        uint32_t w3 = __builtin_amdgcn_perm(f3, f2, sel);
        uint32_t tmp[4] = {w0, w1, w2, w3};
        pb = *(const short8*)tmp;  // B[k=quad*8+j][n=lm] for sk-chunk c
      }

      // ---- O^T += V^T(chunk c) . P^T(chunk c), V^T frags from LDS ----
      {
        const int ac = (c == 0) ? a0s : a1s;
#pragma unroll
        for (int nb = 0; nb < 4; ++nb) {
          short8 vb = *(const short8*)&stag[ac + nb * 1024 + 8192];
          acc[nb] = __builtin_amdgcn_mfma_f32_16x16x32_bf16(vb, pb, acc[nb], 0, 0, 0);
        }
      }
    }
  }

  // ---- epilogue: reduce l across quads, scale, write (wave-independent) ----
  l_i += __shfl_xor(l_i, 16);
  l_i += __shfl_xor(l_i, 32);
  float sc = (0.5f / 0.9f) / l_i;
  float* op = out + (((size_t)(b * Hh + h)) * SQc + qrow) * DVc;
#pragma unroll
  for (int nb = 0; nb < 4; ++nb) {
    float4 o = make_float4(acc[nb][0] * sc, acc[nb][1] * sc,
                           acc[nb][2] * sc, acc[nb][3] * sc);
    *(float4*)(op + nb * 16 + quad * 4) = o;
  }
}

extern "C" void kernel_launch(void* const* d_in, const int* in_sizes, int n_in,
                              void* d_out, int out_size, void* d_ws, size_t ws_size,
                              hipStream_t stream) {
  const float* q = (const float*)d_in[0];
  const float* k = (const float*)d_in[1];
  const float* v = (const float*)d_in[2];
  float* out = (float*)d_out;
  // ws layout: Kh (4 MB) | Kl (4 MB) | Vt (4 MB), tile-contiguous swizzled
  unsigned short* Khg = (unsigned short*)d_ws;
  unsigned short* Klg = Khg + (size_t)Hh * SKc * Dc;
  unsigned short* Vtg = Klg + (size_t)Hh * SKc * Dc;
  prep_kernel<<<dim3(Hh * 32), 256, 0, stream>>>(k, v, Khg, Klg, Vtg);
  attn_main<<<dim3(Bb * Hh * (SQc / 64)), 256, 0, stream>>>(q, Khg, Klg, Vtg, out);
}

// Round 9
// 361.065 us; speedup vs baseline: 2.1794x; 1.0100x over previous
//
#include <hip/hip_runtime.h>
#include <stdint.h>
#include <math.h>

// (B,H,SQ,SK,D,DV) = (2,16,2048,2048,64,64)
// out = (softmax(q k^T) * 0.5) with dropout p=0.1 (jax threefry key 42, partitionable) @ v
// R9: R8 LDS-staged structure + in-block k-split: 512-thread blocks, 8 waves =
// 4 q-groups x 2 k-halves, dual 24 KB staging buffers (48 KB) -> 3 blocks/CU =
// 24 waves/CU (75% cap vs R8's 50%); merge via aliased staging LDS.
namespace {
constexpr int Bb = 2, Hh = 16, SQc = 2048, SKc = 2048, Dc = 64, DVc = 64;
constexpr int TK = 64;

typedef __attribute__((ext_vector_type(8))) short short8;   // MFMA A/B frag (8 bf16)
typedef __attribute__((ext_vector_type(4))) float f32x4;    // MFMA C/D frag

__device__ __forceinline__ uint32_t rotl_(uint32_t x, int r) {
  return __builtin_amdgcn_alignbit(x, x, 32 - r);  // 1-instr rotate
}

// JAX threefry2x32, key=(0,42), partitionable: bits(i)=o0^o1 of threefry((0,42),(0,i)).
// keep iff bits < 0xE6666600 (exact integer form of uniform(bits) < 0.9f). VERIFIED R1-R8.
__device__ __forceinline__ uint32_t tf_bits(uint32_t ctr) {
  const uint32_t ks1 = 42u, ks2 = 0x1BD11BDAu ^ 42u;
  uint32_t x0 = 0u;
  uint32_t x1 = ctr + ks1;
#define TFR(r) { x0 += x1; x1 = rotl_(x1, r); x1 ^= x0; }
  TFR(13) TFR(15) TFR(26) TFR(6)
  x0 += ks1; x1 += ks2 + 1u;
  TFR(17) TFR(29) TFR(16) TFR(24)
  x0 += ks2; x1 += 0u + 2u;
  TFR(13) TFR(15) TFR(26) TFR(6)
  x0 += 0u; x1 += ks1 + 3u;
  TFR(17) TFR(29) TFR(16) TFR(24)
  x0 += ks1; x1 += ks2 + 4u;
  TFR(13) TFR(15) TFR(26) TFR(6)
  x0 += ks2; x1 += 0u + 5u;
#undef TFR
  return x0 ^ x1;
}

__device__ __forceinline__ uint32_t f2bf_u(float x) {  // RNE bf16 (finite x), low 16 bits
  uint32_t u = __float_as_uint(x);
  u += 0x7FFFu + ((u >> 16) & 1u);
  return u >> 16;
}
__device__ __forceinline__ uint32_t bfround(float x) {  // RNE bf16 in bits 31:16
  uint32_t u = __float_as_uint(x);
  return u + 0x7FFFu + ((u >> 16) & 1u);
}

// async global->LDS, 16 B per lane; LDS base wave-uniform, global addr per-lane
__device__ __forceinline__ void gl_lds16(const void* g, void* l) {
  __builtin_amdgcn_global_load_lds(
      (const __attribute__((address_space(1))) unsigned int*)g,
      (__attribute__((address_space(3))) unsigned int*)l, 16, 0, 0);
}
}  // namespace

// Pre-pass: tile-contiguous, XOR-swizzled layouts.
// Kh/Kl tile (h,kt): shorts[4096]; elem (row,col): row*64 + ((col>>3)^(row&7))*8 + (col&7)
// Vt tile  (h,kt): shorts[4096]; elem (dv,skl) = V[kt*64+skl][dv], same swizzle on skl.
__global__ __launch_bounds__(256) void prep_kernel(
    const float* __restrict__ k, const float* __restrict__ v,
    unsigned short* __restrict__ Khg, unsigned short* __restrict__ Klg,
    unsigned short* __restrict__ Vtg) {
  __shared__ float Vs[64 * 65];
  const int t = threadIdx.x;
  const int h = blockIdx.x >> 5;
  const int kt = blockIdx.x & 31;
  const size_t src = ((size_t)h * SKc + kt * 64) * Dc;
  const size_t tb = (size_t)(h * 32 + kt) * 4096;  // tile base (shorts)
#pragma unroll
  for (int i = 0; i < 4; ++i) {
    int idx = t + 256 * i;
    int row = idx >> 4, d0 = (idx & 15) << 2;
    float4 kv = *(const float4*)(k + src + row * Dc + d0);
    uint32_t hx = f2bf_u(kv.x), hy = f2bf_u(kv.y), hz = f2bf_u(kv.z), hw = f2bf_u(kv.w);
    uint32_t lx = f2bf_u(kv.x - __uint_as_float(hx << 16));
    uint32_t ly = f2bf_u(kv.y - __uint_as_float(hy << 16));
    uint32_t lz = f2bf_u(kv.z - __uint_as_float(hz << 16));
    uint32_t lw = f2bf_u(kv.w - __uint_as_float(hw << 16));
    int phys = row * 64 + (((d0 >> 3) ^ (row & 7)) << 3) + (d0 & 7);
    *(ushort4*)(Khg + tb + phys) =
        make_ushort4((unsigned short)hx, (unsigned short)hy, (unsigned short)hz, (unsigned short)hw);
    *(ushort4*)(Klg + tb + phys) =
        make_ushort4((unsigned short)lx, (unsigned short)ly, (unsigned short)lz, (unsigned short)lw);
    float4 vv = *(const float4*)(v + src + row * Dc + d0);  // DVc == Dc
    *(float4*)(&Vs[row * 65 + d0]) = vv;
  }
  __syncthreads();
  const int dv = t >> 2;
  const int j0 = (t & 3) << 1;  // two sk-chunks per thread
#pragma unroll
  for (int g = 0; g < 2; ++g) {
    int chunk = j0 + g;
    unsigned short tmp[8];
#pragma unroll
    for (int s = 0; s < 8; ++s)
      tmp[s] = (unsigned short)f2bf_u(Vs[(chunk * 8 + s) * 65 + dv]);
    *(short8*)(Vtg + tb + dv * 64 + ((chunk ^ (dv & 7)) << 3)) = *(const short8*)tmp;
  }
}

__global__ __launch_bounds__(512, 6) void attn_main(
    const float* __restrict__ q, const unsigned short* __restrict__ Khg,
    const unsigned short* __restrict__ Klg, const unsigned short* __restrict__ Vtg,
    float* __restrict__ out) {
  // dual staging buffers, one per k-half: each Kh [0,4096) Kl [4096,8192)
  // Vt [8192,12288) shorts; total 48 KB. Merge region aliases after the loop.
  __shared__ __align__(16) unsigned short stag[2][12288];

  const int t = threadIdx.x;
  const int lane = t & 63;
  const int w = t >> 6;        // 8 waves
  const int lm = lane & 15;
  const int quad = lane >> 4;
  const int khalf = w & 1;     // k-half this wave processes
  const int qsub = w >> 1;     // q-row group 0..3 (also staging sub-wave id)

  // XCD swizzle: 128 consecutive vids (4 heads) per XCD -> K/V tiles L2-resident
  const int vid = (blockIdx.x & 7) * 128 + (blockIdx.x >> 3);
  const int qt = vid & 31;            // 32 q-tiles of 64 rows
  const int h = (vid >> 5) & 15;
  const int b = vid >> 9;
  const int qrow = qt * 64 + qsub * 16 + lm;

  // ---- Q B-frags (fp32 -> split bf16 in regs), constant over k-loop ----
  short8 qh[2], ql[2];
  {
    const float* qp = q + (((size_t)(b * Hh + h)) * SQc + qrow) * Dc;
#pragma unroll
    for (int c = 0; c < 2; ++c) {
#pragma unroll
      for (int j2 = 0; j2 < 2; ++j2) {
        float4 x = *(const float4*)(qp + c * 32 + quad * 8 + j2 * 4);
        float xs[4] = {x.x, x.y, x.z, x.w};
#pragma unroll
        for (int j = 0; j < 4; ++j) {
          uint32_t hb = f2bf_u(xs[j]);
          float lo = xs[j] - __uint_as_float(hb << 16);
          qh[c][j2 * 4 + j] = (short)hb;
          ql[c][j2 * 4 + j] = (short)f2bf_u(lo);
        }
      }
    }
  }

  const char* kh_t = (const char*)Khg + (size_t)(h * 32) * 8192;
  const char* kl_t = (const char*)Klg + (size_t)(h * 32) * 8192;
  const char* vt_t = (const char*)Vtg + (size_t)(h * 32) * 8192;
  unsigned short* sb = &stag[khalf][0];  // this wave-group's buffer

  f32x4 acc[4] = {{0.f, 0.f, 0.f, 0.f}, {0.f, 0.f, 0.f, 0.f},
                  {0.f, 0.f, 0.f, 0.f}, {0.f, 0.f, 0.f, 0.f}};
  float l_i = 0.f;  // fixed-m (m=0) partial denominator

  // swizzled LDS read offsets (shorts), loop-invariant
  const int e = lm & 7;
  const int a0s = lm * 64 + ((quad ^ e) << 3);        // chunks 0..3
  const int a1s = lm * 64 + (((quad + 4) ^ e) << 3);  // chunks 4..7

  // bpermute byte-addresses for the cross-quad P exchange (constant per lane)
  const int pa0 = ((quad & 1) * 32 + lm) << 2;
  const int pa1 = pa0 + 64;
  const uint32_t sel = (quad >= 2) ? 0x07060302u : 0x05040100u;

  uint32_t ctile = ((uint32_t)((b * Hh + h) * SQc + qrow)) * (uint32_t)SKc +
                   (uint32_t)(khalf * 16 * TK + quad * 4);

#pragma unroll 1
  for (int i = 0; i < 16; ++i, ctile += TK) {
    const int kt = khalf * 16 + i;
    __syncthreads();  // prior tile's ds_reads complete (both groups in lockstep)
    // ---- stage this group's Kh/Kl/Vt tile (24 KB) via global_load_lds ----
    {
      const size_t tile = (size_t)kt * 8192;
#pragma unroll
      for (int r = 0; r < 2; ++r) {
        int off = r * 4096 + qsub * 1024 + lane * 16;
        gl_lds16(kh_t + tile + off, (char*)sb + off);
        gl_lds16(kl_t + tile + off, (char*)sb + 8192 + off);
        gl_lds16(vt_t + tile + off, (char*)sb + 16384 + off);
      }
    }
    __syncthreads();  // staging complete

#pragma unroll
    for (int c = 0; c < 2; ++c) {
      // ---- S^T for K-rows (2c)*16+lm, (2c+1)*16+lm : 3-term split bf16 ----
      f32x4 s0 = {0.f, 0.f, 0.f, 0.f}, s1 = {0.f, 0.f, 0.f, 0.f};
#pragma unroll
      for (int d = 0; d < 2; ++d) {
        const int ad = (d == 0) ? a0s : a1s;
        short8 kh0 = *(const short8*)&sb[ad + (2 * c) * 1024];
        short8 kl0 = *(const short8*)&sb[ad + (2 * c) * 1024 + 4096];
        s0 = __builtin_amdgcn_mfma_f32_16x16x32_bf16(kh0, qh[d], s0, 0, 0, 0);
        s0 = __builtin_amdgcn_mfma_f32_16x16x32_bf16(kl0, qh[d], s0, 0, 0, 0);
        s0 = __builtin_amdgcn_mfma_f32_16x16x32_bf16(kh0, ql[d], s0, 0, 0, 0);
        short8 kh1 = *(const short8*)&sb[ad + (2 * c + 1) * 1024];
        short8 kl1 = *(const short8*)&sb[ad + (2 * c + 1) * 1024 + 4096];
        s1 = __builtin_amdgcn_mfma_f32_16x16x32_bf16(kh1, qh[d], s1, 0, 0, 0);
        s1 = __builtin_amdgcn_mfma_f32_16x16x32_bf16(kl1, qh[d], s1, 0, 0, 0);
        s1 = __builtin_amdgcn_mfma_f32_16x16x32_bf16(kh1, ql[d], s1, 0, 0, 0);
      }

      // ---- p = e^s (fixed m, fp32-safe); inline threefry dropout; pack pairs ----
      uint32_t pkc[4];
#pragma unroll
      for (int r = 0; r < 4; ++r) {
        float p0 = __expf(s0[r]);
        float p1 = __expf(s1[r]);
        l_i += p0 + p1;  // denominator over UNdropped probs
        uint32_t b0 = tf_bits(ctile + (uint32_t)(c * 32 + r));
        uint32_t b1 = tf_bits(ctile + (uint32_t)(c * 32 + 16 + r));
        uint32_t u0 = (b0 < 0xE6666600u) ? bfround(p0) : 0u;
        uint32_t u1 = (b1 < 0xE6666600u) ? bfround(p1) : 0u;
        pkc[r] = __builtin_amdgcn_perm(u1, u0, 0x07060302u);  // (bf(p1)<<16)|bf(p0)
      }

      // ---- P^T B-frag via cross-quad bpermute (no barrier) ----
      short8 pb;
      {
        uint32_t e0 = (uint32_t)__builtin_amdgcn_ds_bpermute(pa0, (int)pkc[0]);
        uint32_t e1 = (uint32_t)__builtin_amdgcn_ds_bpermute(pa0, (int)pkc[1]);
        uint32_t e2 = (uint32_t)__builtin_amdgcn_ds_bpermute(pa0, (int)pkc[2]);
        uint32_t e3 = (uint32_t)__builtin_amdgcn_ds_bpermute(pa0, (int)pkc[3]);
        uint32_t f0 = (uint32_t)__builtin_amdgcn_ds_bpermute(pa1, (int)pkc[0]);
        uint32_t f1 = (uint32_t)__builtin_amdgcn_ds_bpermute(pa1, (int)pkc[1]);
        uint32_t f2 = (uint32_t)__builtin_amdgcn_ds_bpermute(pa1, (int)pkc[2]);
        uint32_t f3 = (uint32_t)__builtin_amdgcn_ds_bpermute(pa1, (int)pkc[3]);
        uint32_t w0 = __builtin_amdgcn_perm(e1, e0, sel);
        uint32_t w1 = __builtin_amdgcn_perm(e3, e2, sel);
        uint32_t w2 = __builtin_amdgcn_perm(f1, f0, sel);
        uint32_t w3 = __builtin_amdgcn_perm(f3, f2, sel);
        uint32_t tmp[4] = {w0, w1, w2, w3};
        pb = *(const short8*)tmp;  // B[k=quad*8+j][n=lm] for sk-chunk c
      }

      // ---- O^T += V^T(chunk c) . P^T(chunk c), V^T frags from LDS ----
      {
        const int ac = (c == 0) ? a0s : a1s;
#pragma unroll
        for (int nb = 0; nb < 4; ++nb) {
          short8 vb = *(const short8*)&sb[ac + nb * 1024 + 8192];
          acc[nb] = __builtin_amdgcn_mfma_f32_16x16x32_bf16(vb, pb, acc[nb], 0, 0, 0);
        }
      }
    }
  }

  // ---- reduce l across quads ----
  l_i += __shfl_xor(l_i, 16);
  l_i += __shfl_xor(l_i, 32);

  // ---- combine the two k-halves via LDS aliased onto staging buffers ----
  float (*Lacc)[16][72] = (float(*)[16][72])&stag[0][0];   // [qsub][lm][dv] 18432 B
  float* Ll = (float*)((char*)&stag[0][0] + 18432);        // [qsub*16+lm] 256 B
  __syncthreads();  // all loop reads of stag complete
  if (khalf == 1) {
#pragma unroll
    for (int nb = 0; nb < 4; ++nb)
      *(f32x4*)&Lacc[qsub][lm][nb * 16 + quad * 4] = acc[nb];
    if (quad == 0) Ll[qsub * 16 + lm] = l_i;
  }
  __syncthreads();
  if (khalf == 0) {
    float lt = l_i + Ll[qsub * 16 + lm];
    float sc = (0.5f / 0.9f) / lt;
    float* op = out + (((size_t)(b * Hh + h)) * SQc + qrow) * DVc;
#pragma unroll
    for (int nb = 0; nb < 4; ++nb) {
      f32x4 other = *(const f32x4*)&Lacc[qsub][lm][nb * 16 + quad * 4];
      float4 o = make_float4((acc[nb][0] + other[0]) * sc, (acc[nb][1] + other[1]) * sc,
                             (acc[nb][2] + other[2]) * sc, (acc[nb][3] + other[3]) * sc);
      *(float4*)(op + nb * 16 + quad * 4) = o;
    }
  }
}

extern "C" void kernel_launch(void* const* d_in, const int* in_sizes, int n_in,
                              void* d_out, int out_size, void* d_ws, size_t ws_size,
                              hipStream_t stream) {
  const float* q = (const float*)d_in[0];
  const float* k = (const float*)d_in[1];
  const float* v = (const float*)d_in[2];
  float* out = (float*)d_out;
  // ws layout: Kh (4 MB) | Kl (4 MB) | Vt (4 MB), tile-contiguous swizzled
  unsigned short* Khg = (unsigned short*)d_ws;
  unsigned short* Klg = Khg + (size_t)Hh * SKc * Dc;
  unsigned short* Vtg = Klg + (size_t)Hh * SKc * Dc;
  prep_kernel<<<dim3(Hh * 32), 256, 0, stream>>>(k, v, Khg, Klg, Vtg);
  attn_main<<<dim3(Bb * Hh * (SQc / 64)), 512, 0, stream>>>(q, Khg, Klg, Vtg, out);
}

// Round 10
// 359.693 us; speedup vs baseline: 2.1877x; 1.0038x over previous
//
#include <hip/hip_runtime.h>
#include <stdint.h>
#include <math.h>

// (B,H,SQ,SK,D,DV) = (2,16,2048,2048,64,64)
// out = (softmax(q k^T) * 0.5) with dropout p=0.1 (jax threefry key 42, partitionable) @ v
// R10: R9 structure + VALU-instr shaving (kernel is VALU-issue-bound: R6 vs R9 both
// ~280us busy): add3-fused threefry injections, v_cvt_pk_bf16_f32 packing,
// log2e folded into Q so p = exp2(s) directly.
namespace {
constexpr int Bb = 2, Hh = 16, SQc = 2048, SKc = 2048, Dc = 64, DVc = 64;
constexpr int TK = 64;
constexpr float LOG2E = 1.4426950408889634f;

typedef __attribute__((ext_vector_type(8))) short short8;   // MFMA A/B frag (8 bf16)
typedef __attribute__((ext_vector_type(4))) float f32x4;    // MFMA C/D frag

__device__ __forceinline__ uint32_t rotl_(uint32_t x, int r) {
  return __builtin_amdgcn_alignbit(x, x, 32 - r);  // 1-instr rotate
}

// JAX threefry2x32, key=(0,42), partitionable: bits(i)=o0^o1 of threefry((0,42),(0,i)).
// keep iff bits < 0xE6666600 (exact integer form of uniform(bits) < 0.9f). VERIFIED R1-R9.
// Injection adds fused with the following round's x0-add (v_add3_u32); mod-2^32
// associativity keeps it bit-exact.
__device__ __forceinline__ uint32_t tf_bits(uint32_t ctr) {
  const uint32_t KS1 = 42u, KS2 = 0x1BD11BF0u;  // 0x1BD11BDA ^ 42
  uint32_t x0, x1;
  x1 = ctr + KS1;
  // group 1 (rot 13,15,26,6); x0 starts at 0 so first add folds
  x0 = x1;        x1 = rotl_(x1, 13); x1 ^= x0;
  x0 += x1;       x1 = rotl_(x1, 15); x1 ^= x0;
  x0 += x1;       x1 = rotl_(x1, 26); x1 ^= x0;
  x0 += x1;       x1 = rotl_(x1,  6); x1 ^= x0;
  // inject (KS1, KS2+1), fused
  x1 += KS2 + 1u;
  x0 += KS1 + x1; x1 = rotl_(x1, 17); x1 ^= x0;
  x0 += x1;       x1 = rotl_(x1, 29); x1 ^= x0;
  x0 += x1;       x1 = rotl_(x1, 16); x1 ^= x0;
  x0 += x1;       x1 = rotl_(x1, 24); x1 ^= x0;
  // inject (KS2, 0+2), fused
  x1 += 2u;
  x0 += KS2 + x1; x1 = rotl_(x1, 13); x1 ^= x0;
  x0 += x1;       x1 = rotl_(x1, 15); x1 ^= x0;
  x0 += x1;       x1 = rotl_(x1, 26); x1 ^= x0;
  x0 += x1;       x1 = rotl_(x1,  6); x1 ^= x0;
  // inject (0, KS1+3)
  x1 += KS1 + 3u;
  x0 += x1;       x1 = rotl_(x1, 17); x1 ^= x0;
  x0 += x1;       x1 = rotl_(x1, 29); x1 ^= x0;
  x0 += x1;       x1 = rotl_(x1, 16); x1 ^= x0;
  x0 += x1;       x1 = rotl_(x1, 24); x1 ^= x0;
  // inject (KS1, KS2+4), fused
  x1 += KS2 + 4u;
  x0 += KS1 + x1; x1 = rotl_(x1, 13); x1 ^= x0;
  x0 += x1;       x1 = rotl_(x1, 15); x1 ^= x0;
  x0 += x1;       x1 = rotl_(x1, 26); x1 ^= x0;
  x0 += x1;       x1 = rotl_(x1,  6); x1 ^= x0;
  // final inject (KS2, 0+5)
  return (x0 + KS2) ^ (x1 + 5u);
}

__device__ __forceinline__ uint32_t f2bf_u(float x) {  // RNE bf16 (finite x), low 16 bits
  uint32_t u = __float_as_uint(x);
  u += 0x7FFFu + ((u >> 16) & 1u);
  return u >> 16;
}

// async global->LDS, 16 B per lane; LDS base wave-uniform, global addr per-lane
__device__ __forceinline__ void gl_lds16(const void* g, void* l) {
  __builtin_amdgcn_global_load_lds(
      (const __attribute__((address_space(1))) unsigned int*)g,
      (__attribute__((address_space(3))) unsigned int*)l, 16, 0, 0);
}
}  // namespace

// Pre-pass: tile-contiguous, XOR-swizzled layouts.
// Kh/Kl tile (h,kt): shorts[4096]; elem (row,col): row*64 + ((col>>3)^(row&7))*8 + (col&7)
// Vt tile  (h,kt): shorts[4096]; elem (dv,skl) = V[kt*64+skl][dv], same swizzle on skl.
__global__ __launch_bounds__(256) void prep_kernel(
    const float* __restrict__ k, const float* __restrict__ v,
    unsigned short* __restrict__ Khg, unsigned short* __restrict__ Klg,
    unsigned short* __restrict__ Vtg) {
  __shared__ float Vs[64 * 65];
  const int t = threadIdx.x;
  const int h = blockIdx.x >> 5;
  const int kt = blockIdx.x & 31;
  const size_t src = ((size_t)h * SKc + kt * 64) * Dc;
  const size_t tb = (size_t)(h * 32 + kt) * 4096;  // tile base (shorts)
#pragma unroll
  for (int i = 0; i < 4; ++i) {
    int idx = t + 256 * i;
    int row = idx >> 4, d0 = (idx & 15) << 2;
    float4 kv = *(const float4*)(k + src + row * Dc + d0);
    uint32_t hx = f2bf_u(kv.x), hy = f2bf_u(kv.y), hz = f2bf_u(kv.z), hw = f2bf_u(kv.w);
    uint32_t lx = f2bf_u(kv.x - __uint_as_float(hx << 16));
    uint32_t ly = f2bf_u(kv.y - __uint_as_float(hy << 16));
    uint32_t lz = f2bf_u(kv.z - __uint_as_float(hz << 16));
    uint32_t lw = f2bf_u(kv.w - __uint_as_float(hw << 16));
    int phys = row * 64 + (((d0 >> 3) ^ (row & 7)) << 3) + (d0 & 7);
    *(ushort4*)(Khg + tb + phys) =
        make_ushort4((unsigned short)hx, (unsigned short)hy, (unsigned short)hz, (unsigned short)hw);
    *(ushort4*)(Klg + tb + phys) =
        make_ushort4((unsigned short)lx, (unsigned short)ly, (unsigned short)lz, (unsigned short)lw);
    float4 vv = *(const float4*)(v + src + row * Dc + d0);  // DVc == Dc
    *(float4*)(&Vs[row * 65 + d0]) = vv;
  }
  __syncthreads();
  const int dv = t >> 2;
  const int j0 = (t & 3) << 1;  // two sk-chunks per thread
#pragma unroll
  for (int g = 0; g < 2; ++g) {
    int chunk = j0 + g;
    unsigned short tmp[8];
#pragma unroll
    for (int s = 0; s < 8; ++s)
      tmp[s] = (unsigned short)f2bf_u(Vs[(chunk * 8 + s) * 65 + dv]);
    *(short8*)(Vtg + tb + dv * 64 + ((chunk ^ (dv & 7)) << 3)) = *(const short8*)tmp;
  }
}

__global__ __launch_bounds__(512, 6) void attn_main(
    const float* __restrict__ q, const unsigned short* __restrict__ Khg,
    const unsigned short* __restrict__ Klg, const unsigned short* __restrict__ Vtg,
    float* __restrict__ out) {
  // dual staging buffers, one per k-half: each Kh [0,4096) Kl [4096,8192)
  // Vt [8192,12288) shorts; total 48 KB. Merge region aliases after the loop.
  __shared__ __align__(16) unsigned short stag[2][12288];

  const int t = threadIdx.x;
  const int lane = t & 63;
  const int w = t >> 6;        // 8 waves
  const int lm = lane & 15;
  const int quad = lane >> 4;
  const int khalf = w & 1;     // k-half this wave processes
  const int qsub = w >> 1;     // q-row group 0..3 (also staging sub-wave id)

  // XCD swizzle: 128 consecutive vids (4 heads) per XCD -> K/V tiles L2-resident
  const int vid = (blockIdx.x & 7) * 128 + (blockIdx.x >> 3);
  const int qt = vid & 31;            // 32 q-tiles of 64 rows
  const int h = (vid >> 5) & 15;
  const int b = vid >> 9;
  const int qrow = qt * 64 + qsub * 16 + lm;

  // ---- Q B-frags (fp32 * log2e -> split bf16 in regs), constant over k-loop ----
  short8 qh[2], ql[2];
  {
    const float* qp = q + (((size_t)(b * Hh + h)) * SQc + qrow) * Dc;
#pragma unroll
    for (int c = 0; c < 2; ++c) {
#pragma unroll
      for (int j2 = 0; j2 < 2; ++j2) {
        float4 x = *(const float4*)(qp + c * 32 + quad * 8 + j2 * 4);
        float xs[4] = {x.x * LOG2E, x.y * LOG2E, x.z * LOG2E, x.w * LOG2E};
#pragma unroll
        for (int j = 0; j < 4; ++j) {
          uint32_t hb = f2bf_u(xs[j]);
          float lo = xs[j] - __uint_as_float(hb << 16);
          qh[c][j2 * 4 + j] = (short)hb;
          ql[c][j2 * 4 + j] = (short)f2bf_u(lo);
        }
      }
    }
  }

  const char* kh_t = (const char*)Khg + (size_t)(h * 32) * 8192;
  const char* kl_t = (const char*)Klg + (size_t)(h * 32) * 8192;
  const char* vt_t = (const char*)Vtg + (size_t)(h * 32) * 8192;
  unsigned short* sb = &stag[khalf][0];  // this wave-group's buffer

  f32x4 acc[4] = {{0.f, 0.f, 0.f, 0.f}, {0.f, 0.f, 0.f, 0.f},
                  {0.f, 0.f, 0.f, 0.f}, {0.f, 0.f, 0.f, 0.f}};
  float l_i = 0.f;  // fixed-m (m=0) partial denominator

  // swizzled LDS read offsets (shorts), loop-invariant
  const int e = lm & 7;
  const int a0s = lm * 64 + ((quad ^ e) << 3);        // chunks 0..3
  const int a1s = lm * 64 + (((quad + 4) ^ e) << 3);  // chunks 4..7

  // bpermute byte-addresses for the cross-quad P exchange (constant per lane)
  const int pa0 = ((quad & 1) * 32 + lm) << 2;
  const int pa1 = pa0 + 64;
  const uint32_t sel = (quad >= 2) ? 0x07060302u : 0x05040100u;

  uint32_t ctile = ((uint32_t)((b * Hh + h) * SQc + qrow)) * (uint32_t)SKc +
                   (uint32_t)(khalf * 16 * TK + quad * 4);

#pragma unroll 1
  for (int i = 0; i < 16; ++i, ctile += TK) {
    const int kt = khalf * 16 + i;
    __syncthreads();  // prior tile's ds_reads complete (both groups in lockstep)
    // ---- stage this group's Kh/Kl/Vt tile (24 KB) via global_load_lds ----
    {
      const size_t tile = (size_t)kt * 8192;
#pragma unroll
      for (int r = 0; r < 2; ++r) {
        int off = r * 4096 + qsub * 1024 + lane * 16;
        gl_lds16(kh_t + tile + off, (char*)sb + off);
        gl_lds16(kl_t + tile + off, (char*)sb + 8192 + off);
        gl_lds16(vt_t + tile + off, (char*)sb + 16384 + off);
      }
    }
    __syncthreads();  // staging complete

#pragma unroll
    for (int c = 0; c < 2; ++c) {
      // ---- S^T for K-rows (2c)*16+lm, (2c+1)*16+lm : 3-term split bf16 ----
      f32x4 s0 = {0.f, 0.f, 0.f, 0.f}, s1 = {0.f, 0.f, 0.f, 0.f};
#pragma unroll
      for (int d = 0; d < 2; ++d) {
        const int ad = (d == 0) ? a0s : a1s;
        short8 kh0 = *(const short8*)&sb[ad + (2 * c) * 1024];
        short8 kl0 = *(const short8*)&sb[ad + (2 * c) * 1024 + 4096];
        s0 = __builtin_amdgcn_mfma_f32_16x16x32_bf16(kh0, qh[d], s0, 0, 0, 0);
        s0 = __builtin_amdgcn_mfma_f32_16x16x32_bf16(kl0, qh[d], s0, 0, 0, 0);
        s0 = __builtin_amdgcn_mfma_f32_16x16x32_bf16(kh0, ql[d], s0, 0, 0, 0);
        short8 kh1 = *(const short8*)&sb[ad + (2 * c + 1) * 1024];
        short8 kl1 = *(const short8*)&sb[ad + (2 * c + 1) * 1024 + 4096];
        s1 = __builtin_amdgcn_mfma_f32_16x16x32_bf16(kh1, qh[d], s1, 0, 0, 0);
        s1 = __builtin_amdgcn_mfma_f32_16x16x32_bf16(kl1, qh[d], s1, 0, 0, 0);
        s1 = __builtin_amdgcn_mfma_f32_16x16x32_bf16(kh1, ql[d], s1, 0, 0, 0);
      }

      // ---- p = exp2(s) (Q pre-scaled by log2e; fixed m, fp32-safe);
      //      threefry dropout as float cndmask; HW pack v_cvt_pk_bf16_f32 ----
      uint32_t pkc[4];
#pragma unroll
      for (int r = 0; r < 4; ++r) {
        float p0 = __builtin_amdgcn_exp2f(s0[r]);
        float p1 = __builtin_amdgcn_exp2f(s1[r]);
        l_i += p0 + p1;  // denominator over UNdropped probs
        uint32_t b0 = tf_bits(ctile + (uint32_t)(c * 32 + r));
        uint32_t b1 = tf_bits(ctile + (uint32_t)(c * 32 + 16 + r));
        float k0 = (b0 < 0xE6666600u) ? p0 : 0.0f;
        float k1 = (b1 < 0xE6666600u) ? p1 : 0.0f;
        uint32_t pk;
        asm("v_cvt_pk_bf16_f32 %0, %1, %2" : "=v"(pk) : "v"(k0), "v"(k1));
        pkc[r] = pk;  // (bf16(k1)<<16)|bf16(k0), RNE
      }

      // ---- P^T B-frag via cross-quad bpermute (no barrier) ----
      short8 pb;
      {
        uint32_t e0 = (uint32_t)__builtin_amdgcn_ds_bpermute(pa0, (int)pkc[0]);
        uint32_t e1 = (uint32_t)__builtin_amdgcn_ds_bpermute(pa0, (int)pkc[1]);
        uint32_t e2 = (uint32_t)__builtin_amdgcn_ds_bpermute(pa0, (int)pkc[2]);
        uint32_t e3 = (uint32_t)__builtin_amdgcn_ds_bpermute(pa0, (int)pkc[3]);
        uint32_t f0 = (uint32_t)__builtin_amdgcn_ds_bpermute(pa1, (int)pkc[0]);
        uint32_t f1 = (uint32_t)__builtin_amdgcn_ds_bpermute(pa1, (int)pkc[1]);
        uint32_t f2 = (uint32_t)__builtin_amdgcn_ds_bpermute(pa1, (int)pkc[2]);
        uint32_t f3 = (uint32_t)__builtin_amdgcn_ds_bpermute(pa1, (int)pkc[3]);
        uint32_t w0 = __builtin_amdgcn_perm(e1, e0, sel);
        uint32_t w1 = __builtin_amdgcn_perm(e3, e2, sel);
        uint32_t w2 = __builtin_amdgcn_perm(f1, f0, sel);
        uint32_t w3 = __builtin_amdgcn_perm(f3, f2, sel);
        uint32_t tmp[4] = {w0, w1, w2, w3};
        pb = *(const short8*)tmp;  // B[k=quad*8+j][n=lm] for sk-chunk c
      }

      // ---- O^T += V^T(chunk c) . P^T(chunk c), V^T frags from LDS ----
      {
        const int ac = (c == 0) ? a0s : a1s;
#pragma unroll
        for (int nb = 0; nb < 4; ++nb) {
          short8 vb = *(const short8*)&sb[ac + nb * 1024 + 8192];
          acc[nb] = __builtin_amdgcn_mfma_f32_16x16x32_bf16(vb, pb, acc[nb], 0, 0, 0);
        }
      }
    }
  }

  // ---- reduce l across quads ----
  l_i += __shfl_xor(l_i, 16);
  l_i += __shfl_xor(l_i, 32);

  // ---- combine the two k-halves via LDS aliased onto staging buffers ----
  float (*Lacc)[16][72] = (float(*)[16][72])&stag[0][0];   // [qsub][lm][dv] 18432 B
  float* Ll = (float*)((char*)&stag[0][0] + 18432);        // [qsub*16+lm] 256 B
  __syncthreads();  // all loop reads of stag complete
  if (khalf == 1) {
#pragma unroll
    for (int nb = 0; nb < 4; ++nb)
      *(f32x4*)&Lacc[qsub][lm][nb * 16 + quad * 4] = acc[nb];
    if (quad == 0) Ll[qsub * 16 + lm] = l_i;
  }
  __syncthreads();
  if (khalf == 0) {
    float lt = l_i + Ll[qsub * 16 + lm];
    float sc = (0.5f / 0.9f) / lt;
    float* op = out + (((size_t)(b * Hh + h)) * SQc + qrow) * DVc;
#pragma unroll
    for (int nb = 0; nb < 4; ++nb) {
      f32x4 other = *(const f32x4*)&Lacc[qsub][lm][nb * 16 + quad * 4];
      float4 o = make_float4((acc[nb][0] + other[0]) * sc, (acc[nb][1] + other[1]) * sc,
                             (acc[nb][2] + other[2]) * sc, (acc[nb][3] + other[3]) * sc);
      *(float4*)(op + nb * 16 + quad * 4) = o;
    }
  }
}

extern "C" void kernel_launch(void* const* d_in, const int* in_sizes, int n_in,
                              void* d_out, int out_size, void* d_ws, size_t ws_size,
                              hipStream_t stream) {
  const float* q = (const float*)d_in[0];
  const float* k = (const float*)d_in[1];
  const float* v = (const float*)d_in[2];
  float* out = (float*)d_out;
  // ws layout: Kh (4 MB) | Kl (4 MB) | Vt (4 MB), tile-contiguous swizzled
  unsigned short* Khg = (unsigned short*)d_ws;
  unsigned short* Klg = Khg + (size_t)Hh * SKc * Dc;
  unsigned short* Vtg = Klg + (size_t)Hh * SKc * Dc;
  prep_kernel<<<dim3(Hh * 32), 256, 0, stream>>>(k, v, Khg, Klg, Vtg);
  attn_main<<<dim3(Bb * Hh * (SQc / 64)), 512, 0, stream>>>(q, Khg, Klg, Vtg, out);
}